// Round 11
// baseline (13575.607 us; speedup 1.0000x reference)
//
#include <hip/hip_runtime.h>
#include <hip/hip_fp16.h>

#define Tt 1024
#define Ii 256
#define Hh 512
#define Cc 10
#define SPINMAX (1 << 20)

typedef _Float16 f16;
typedef _Float16 f16x8 __attribute__((ext_vector_type(8)));
typedef _Float16 f16x4 __attribute__((ext_vector_type(4)));
typedef _Float16 f16x2 __attribute__((ext_vector_type(2)));
typedef float    f32x4 __attribute__((ext_vector_type(4)));

// ---- ws byte offsets ----
#define OFF_WH1   32768u
#define OFF_WH2   557056u
#define OFF_XWR   1081344u    // f16 [16][8][8192]  xw ring  (32 tiles x 256)
#define OFF_H1R   3178496u    // f16 [16][8][8192]  h1 ring  (row-major 16x512)
#define OFF_PAR   5275648u    // f16 [16][8][8192]  par ring (32 tiles x 256)

#define FLG(i) (FL + (size_t)(i) * 32)   // flags padded to 128B each

static __device__ __forceinline__ f32x4 mfma16(f16x8 a, f16x8 b, f32x4 c) {
  return __builtin_amdgcn_mfma_f32_16x16x32_f16(a, b, c, 0, 0, 0);
}
static __device__ __forceinline__ float fast_tanh(float v) {
  float e = __expf(2.0f * v);
  return 1.0f - 2.0f / (e + 1.0f);
}
static __device__ __forceinline__ int ldflag(const int* p) {
  return __hip_atomic_load(p, __ATOMIC_RELAXED, __HIP_MEMORY_SCOPE_AGENT);
}
static __device__ __forceinline__ void stflag(int* p, int v) {
  __hip_atomic_store(p, v, __ATOMIC_RELAXED, __HIP_MEMORY_SCOPE_AGENT);
}
static __device__ __forceinline__ f16x4 ld64cc(const f16* p) {
  union { unsigned long long u; f16x4 v; } U;
  U.u = __hip_atomic_load((const unsigned long long*)p, __ATOMIC_RELAXED, __HIP_MEMORY_SCOPE_AGENT);
  return U.v;
}
static __device__ __forceinline__ void st64cc(f16* p, f16x4 v) {
  union { unsigned long long u; f16x4 v; } U; U.v = v;
  __hip_atomic_store((unsigned long long*)p, U.u, __ATOMIC_RELAXED, __HIP_MEMORY_SCOPE_AGENT);
}
static __device__ __forceinline__ f16x8 ld128cc(const f16* p) {
  union { unsigned long long u[2]; f16x8 v; } U;
  U.u[0] = __hip_atomic_load((const unsigned long long*)p,     __ATOMIC_RELAXED, __HIP_MEMORY_SCOPE_AGENT);
  U.u[1] = __hip_atomic_load((const unsigned long long*)p + 1, __ATOMIC_RELAXED, __HIP_MEMORY_SCOPE_AGENT);
  return U.v;
}
static __device__ __forceinline__ void stu32cc(unsigned* p, unsigned v) {
  __hip_atomic_store(p, v, __ATOMIC_RELAXED, __HIP_MEMORY_SCOPE_AGENT);
}
static __device__ __forceinline__ int imin(int a, int b) { return a < b ? a : b; }

#define VMFENCE() asm volatile("s_waitcnt vmcnt(0)" ::: "memory")
#define LBAR() do { asm volatile("s_waitcnt lgkmcnt(0)" ::: "memory"); \
                    __builtin_amdgcn_s_barrier(); \
                    __builtin_amdgcn_sched_barrier(0); } while (0)

__global__ void prep_weights(const float* __restrict__ w_hh1,
                             const float* __restrict__ w_hh2,
                             char* __restrict__ ws) {
  f16* wh1 = (f16*)(ws + OFF_WH1);
  f16* wh2 = (f16*)(ws + OFF_WH2);
  int i = blockIdx.x * 512 + threadIdx.x;
  if (i < 512 * 512) { wh1[i] = (f16)w_hh1[i]; wh2[i] = (f16)w_hh2[i]; }
}

#define FEEDLOAD(DST, SLOT) {                                                     \
    const f16* fs_ = fring + ((size_t)(SLOT) * 8 + bg) * 8192;                    \
    _Pragma("unroll")                                                             \
    for (int nt = 0; nt < 8; ++nt)                                                \
      DST[nt] = ld64cc(fs_ + (wid * 8 + nt) * 256 + lm * 16 + lgrp * 4);          \
  }

// ---- one recurrence step (geometry: 4 waves x 128 cols, 8 tiles/wave) ----
#define BODY(P, FVC, HAVC)                                                        \
  if (!dead) {                                                                    \
    const int p_ = (P);                                                           \
    const int s0_ = p_ & 3;                                                       \
    /* h1-ring overwrite guard (H1 only), raws issued 1 step earlier */           \
    if (isH1 && p_ >= 16) {                                                       \
      int g_ = imin(imin(rGa, rGb), imin(rGc, rGd));                              \
      if (g_ < p_ - 15) {                                                         \
        const int* g0 = FLG(80 + bg * 16 + s0_ * 4);                              \
        int v_ = 0, sp_ = 0;                                                      \
        do { v_ = imin(imin(ldflag(g0), ldflag(g0 + 32)),                         \
                       imin(ldflag(g0 + 64), ldflag(g0 + 96)));                   \
             if (v_ >= p_ - 15) break; __builtin_amdgcn_s_sleep(2);               \
        } while (++sp_ < SPINMAX);                                                \
        if (v_ < p_ - 15) dead = 1;                                               \
      }                                                                           \
    }                                                                             \
    /* slow-path feed (prefetch missed) */                                        \
    if (!(HAVC) && !dead) {                                                       \
      int v_ = 0, sp_ = 0;                                                        \
      if (isH1) {                                                                 \
        const int* f0 = FLG(16 + bg * 8 + s0_ * 2);                               \
        do { v_ = imin(ldflag(f0), ldflag(f0 + 32)); if (v_ >= p_ + 1) break;     \
             __builtin_amdgcn_s_sleep(2); } while (++sp_ < SPINMAX);              \
      } else {                                                                    \
        const int* f0 = FLG(80 + bg * 16 + s0_ * 4);                              \
        do { v_ = imin(imin(ldflag(f0), ldflag(f0 + 32)),                         \
                       imin(ldflag(f0 + 64), ldflag(f0 + 96)));                   \
             if (v_ >= p_ + 1) break; __builtin_amdgcn_s_sleep(2);                \
        } while (++sp_ < SPINMAX);                                                \
      }                                                                           \
      if (v_ < p_ + 1) dead = 1;                                                  \
      FEEDLOAD(FVC, p_ & 15)                                                      \
    }                                                                             \
    /* stream kc14,15 (issued early, consumed last -> hidden under MFMAs) */      \
    f16x8 w14_[8], w15_[8];                                                       \
    if (p_ > 0) {                                                                 \
      _Pragma("unroll")                                                           \
      for (int nt = 0; nt < 8; ++nt) {                                            \
        w14_[nt] = *(const f16x8*)&whh[(size_t)(wcol0 + nt * 16 + lm) * 512 + 14 * 32 + lk8]; \
        w15_[nt] = *(const f16x8*)&whh[(size_t)(wcol0 + nt * 16 + lm) * 512 + 15 * 32 + lk8]; \
      }                                                                           \
    }                                                                             \
    f32x4 acc[8];                                                                 \
    _Pragma("unroll")                                                             \
    for (int nt = 0; nt < 8; ++nt) acc[nt] = f32x4{0.f, 0.f, 0.f, 0.f};           \
    if (p_ > 0) {                                                                 \
      _Pragma("unroll")                                                           \
      for (int kc = 0; kc < 16; ++kc) {                                           \
        f16x8 A_ = *(const f16x8*)&sH[lm * 520 + kc * 32 + lk8];                  \
        _Pragma("unroll")                                                         \
        for (int nt = 0; nt < 8; ++nt) {                                          \
          f16x8 B_;                                                               \
          if (kc < 4)       B_ = *(const f16x8*)&sB[((size_t)(kc * 4 + lgrp) * 512 + wcol0 + nt * 16 + lm) * 8]; \
          else if (kc < 14) B_ = wbr[kc - 4][nt];                                 \
          else if (kc == 14) B_ = w14_[nt];                                       \
          else              B_ = w15_[nt];                                        \
          acc[nt] = mfma16(A_, B_, acc[nt]);                                      \
        }                                                                         \
      }                                                                           \
    }                                                                             \
    LBAR(); /* state reads complete before overwrite */                           \
    if (p_ > 0) {                                                                 \
      if (isH1) {                                                                 \
        if ((p_ & 3) == 0) { VMFENCE(); if (tid == 0) stflag(progF, p_); }        \
      } else {                                                                    \
        if ((p_ & 1) == 0 && tid == 0) stflag(progF, p_);                         \
      }                                                                           \
    }                                                                             \
    _Pragma("unroll")                                                             \
    for (int nt = 0; nt < 8; ++nt) {                                              \
      acc[nt][0] += (float)FVC[nt][0]; acc[nt][1] += (float)FVC[nt][1];           \
      acc[nt][2] += (float)FVC[nt][2]; acc[nt][3] += (float)FVC[nt][3];           \
    }                                                                             \
    /* refill this parity buffer with feed p+2 (flag raws 1 step old) */          \
    HAVC = 0;                                                                     \
    if (p_ + 2 < Tt && !dead) {                                                   \
      int ca_ = isH1 ? imin(rFa, rFb) : imin(imin(rFa, rFb), imin(rFc, rFd));     \
      if (ca_ >= p_ + 3) { FEEDLOAD(FVC, (p_ + 2) & 15) HAVC = 1; }               \
    }                                                                             \
    /* epilogue: tanh -> LDS state (+ h1 ring for H1) */                          \
    unsigned* ring32_ = (unsigned*)(h1r + ((size_t)(p_ & 15) * 8 + bg) * 8192);   \
    _Pragma("unroll")                                                             \
    for (int nt = 0; nt < 8; ++nt) {                                              \
      const int cp_ = (wcol0 + nt * 16 + lm) >> 1;                                \
      float v0_ = fast_tanh(acc[nt][0]), v1_ = fast_tanh(acc[nt][1]);             \
      float v2_ = fast_tanh(acc[nt][2]), v3_ = fast_tanh(acc[nt][3]);             \
      float o0_ = __shfl_xor(v0_, 1, 64), o1_ = __shfl_xor(v1_, 1, 64);           \
      float o2_ = __shfl_xor(v2_, 1, 64), o3_ = __shfl_xor(v3_, 1, 64);           \
      float m_[4] = {v0_, v1_, v2_, v3_}, q_[4] = {o0_, o1_, o2_, o3_};           \
      _Pragma("unroll")                                                           \
      for (int r2 = 0; r2 < 2; ++r2) {                                            \
        const int rr_ = rlo + r2, row_ = lgrp * 4 + rr_;                          \
        float ve_ = (lane & 1) ? q_[rr_] : m_[rr_];                               \
        float vo_ = (lane & 1) ? m_[rr_] : q_[rr_];                               \
        union { f16x2 h; unsigned u; } P_; P_.h = f16x2{(f16)ve_, (f16)vo_};      \
        sH32[row_ * 260 + cp_] = P_.u;                                            \
        if (isH1) stu32cc(ring32_ + row_ * 256 + cp_, P_.u);                      \
      }                                                                           \
    }                                                                             \
    /* issue flag raws for next step (evaluated there: latency hidden) */         \
    if (isH1) {                                                                   \
      const int* f0 = FLG(16 + bg * 8 + (((p_ + 3) & 3)) * 2);                    \
      rFa = ldflag(f0); rFb = ldflag(f0 + 32);                                    \
      const int* g0 = FLG(80 + bg * 16 + (((p_ + 1) & 3)) * 4);                   \
      rGa = ldflag(g0); rGb = ldflag(g0 + 32);                                    \
      rGc = ldflag(g0 + 64); rGd = ldflag(g0 + 96);                               \
    } else {                                                                      \
      const int* f0 = FLG(80 + bg * 16 + (((p_ + 3) & 3)) * 4);                   \
      rFa = ldflag(f0); rFb = ldflag(f0 + 32);                                    \
      rFc = ldflag(f0 + 64); rFd = ldflag(f0 + 96);                               \
    }                                                                             \
    LBAR(); /* state writes visible */                                            \
  }

__global__ __launch_bounds__(256) __attribute__((amdgpu_waves_per_eu(1)))
void rnn_main(
    const float* __restrict__ x,
    const float* __restrict__ w_ih1, const float* __restrict__ w_ih2,
    const float* __restrict__ b_ih1, const float* __restrict__ b_hh1,
    const float* __restrict__ b_ih2, const float* __restrict__ b_hh2,
    const float* __restrict__ w_out, const float* __restrict__ b_out,
    float* __restrict__ out, char* __restrict__ ws)
{
  __shared__ __align__(16) char LS[147712];

  int* FL = (int*)ws;
  const f16* wh1f = (const f16*)(ws + OFF_WH1);
  const f16* wh2f = (const f16*)(ws + OFF_WH2);
  f16* xwr  = (f16*)(ws + OFF_XWR);
  f16* h1r  = (f16*)(ws + OFF_H1R);
  f16* parr = (f16*)(ws + OFF_PAR);

  const int bid  = blockIdx.x;
  const int tid  = threadIdx.x;
  const int wid  = tid >> 6;       // 0..3
  const int lane = tid & 63;
  const int lm   = lane & 15;
  const int lgrp = lane >> 4;
  const int lk8  = lgrp * 8;
  const int rlo  = (lane & 1) * 2;

  if (bid < 16) {
    // ============ H1 (0..7) / H2 (8..15): full-width recurrence ============
    const bool isH1 = (bid < 8);
    const int bg = bid & 7;
    f16* sB = (f16*)LS;                    // kc0..3 frag layout (128KB)
    f16* sH = (f16*)(LS + 131072);         // [16][520] state
    unsigned* sH32 = (unsigned*)sH;
    const f16* whh = isH1 ? wh1f : wh2f;
    const f16* fring = isH1 ? xwr : parr;
    int* progF = FLG(isH1 ? bg : 8 + bg);
    const int wcol0 = wid * 128;           // 128 cols per wave

    for (int i = tid; i < 8192; i += 256) {
      const int kc = i >> 11, grp = (i >> 9) & 3, col = i & 511;
      *(f16x8*)&sB[(size_t)i * 8] =
        *(const f16x8*)&whh[(size_t)col * 512 + kc * 32 + grp * 8];
    }
    for (int i = tid; i < 16 * 260; i += 256) sH32[i] = 0u;
    // kc4..13 pinned in VGPRs (320/lane)
    f16x8 wbr[10][8];
    #pragma unroll
    for (int kr = 0; kr < 10; ++kr) {
      #pragma unroll
      for (int nt = 0; nt < 8; ++nt) {
        wbr[kr][nt] = *(const f16x8*)&whh[(size_t)(wcol0 + nt * 16 + lm) * 512 + (kr + 4) * 32 + lk8];
        asm volatile("" : "+v"(wbr[kr][nt]));
      }
    }
    __syncthreads();

    int dead = 0;
    f16x4 fX[8], fY[8];
    int hX = 0, hY = 0;
    int rFa = 0, rFb = 0, rFc = 0, rFd = 0;
    int rGa = 0, rGb = 0, rGc = 0, rGd = 0;

    // prologue: feeds 0 (X) and 1 (Y); bootstrap raws for step-0 refill (set 2)
    {
      int v = 0, sp = 0;
      if (isH1) {
        const int* f0 = FLG(16 + bg * 8 + 0);
        do { v = imin(ldflag(f0), ldflag(f0 + 32)); if (v >= 1) break;
             __builtin_amdgcn_s_sleep(8); } while (++sp < SPINMAX);
      } else {
        const int* f0 = FLG(80 + bg * 16 + 0);
        do { v = imin(imin(ldflag(f0), ldflag(f0 + 32)),
                      imin(ldflag(f0 + 64), ldflag(f0 + 96)));
             if (v >= 1) break; __builtin_amdgcn_s_sleep(8); } while (++sp < SPINMAX);
      }
      if (v < 1) dead = 1;
      FEEDLOAD(fX, 0)
      hX = 1;
      v = 0; sp = 0;
      if (isH1) {
        const int* f0 = FLG(16 + bg * 8 + 1 * 2);
        do { v = imin(ldflag(f0), ldflag(f0 + 32)); if (v >= 2) break;
             __builtin_amdgcn_s_sleep(8); } while (++sp < SPINMAX);
      } else {
        const int* f0 = FLG(80 + bg * 16 + 1 * 4);
        do { v = imin(imin(ldflag(f0), ldflag(f0 + 32)),
                      imin(ldflag(f0 + 64), ldflag(f0 + 96)));
             if (v >= 2) break; __builtin_amdgcn_s_sleep(8); } while (++sp < SPINMAX);
      }
      if (v < 2) dead = 1;
      FEEDLOAD(fY, 1)
      hY = 1;
      if (isH1) {
        const int* a0 = FLG(16 + bg * 8 + 2 * 2);
        rFa = ldflag(a0); rFb = ldflag(a0 + 32);
      } else {
        const int* a0 = FLG(80 + bg * 16 + 2 * 4);
        rFa = ldflag(a0); rFb = ldflag(a0 + 32);
        rFc = ldflag(a0 + 64); rFd = ldflag(a0 + 96);
      }
    }

    for (int p2 = 0; p2 < Tt; p2 += 2) {
      BODY(p2,     fX, hX)
      BODY(p2 + 1, fY, hY)
    }

    VMFENCE();
    if (tid == 0) stflag(progF, Tt + 2);

    if (!isH1) {   // ---- final: out = h2_{T-1} @ w_out^T + b_out ----
      const int rl  = wid * 4 + (lane >> 4);   // row 0..15
      const int l16 = lane & 15;
      const f16* hr = &sH[rl * 520 + l16 * 32];
      f16x8 a0 = *(const f16x8*)hr;
      f16x8 a1 = *(const f16x8*)(hr + 8);
      f16x8 a2 = *(const f16x8*)(hr + 16);
      f16x8 a3 = *(const f16x8*)(hr + 24);
      float hf[32];
      #pragma unroll
      for (int j = 0; j < 8; ++j) {
        hf[j] = (float)a0[j]; hf[8 + j] = (float)a1[j];
        hf[16 + j] = (float)a2[j]; hf[24 + j] = (float)a3[j];
      }
      #pragma unroll
      for (int c = 0; c < Cc; ++c) {
        const float* wr_ = w_out + (size_t)c * Hh + l16 * 32;
        float s = 0.f;
        #pragma unroll
        for (int j4 = 0; j4 < 8; ++j4) {
          float4 w4 = *(const float4*)(wr_ + j4 * 4);
          s += hf[j4*4]*w4.x + hf[j4*4+1]*w4.y + hf[j4*4+2]*w4.z + hf[j4*4+3]*w4.w;
        }
        #pragma unroll
        for (int off = 8; off >= 1; off >>= 1) s += __shfl_xor(s, off, 64);
        if (l16 == 0) out[(bg * 16 + rl) * Cc + c] = s + b_out[c];
      }
    }
  } else if (bid < 144) {
    // ============ 2A (16..143): par_q = h1_q @ w_ih2^T + b2 (4 sets x 4 cb) ============
    const int idx = bid - 16;
    const int bg = idx >> 4, r16 = idx & 15;
    const int set = r16 >> 2, cb = r16 & 3;
    f16* sW = (f16*)LS;                    // [16kc][4grp][128col][8] (128KB)
    f16* sA = (f16*)(LS + 131072);         // [16][520] staged h1

    for (int i = tid; i < 8192; i += 256) {
      const int kc = i >> 9, grp = (i >> 7) & 3, cl = i & 127;
      const float* sp = w_ih2 + (size_t)(cb * 128 + cl) * 512 + kc * 32 + grp * 8;
      float4 a = *(const float4*)sp, b = *(const float4*)(sp + 4);
      *(f16x8*)&sW[(size_t)i * 8] =
        f16x8{(f16)a.x,(f16)a.y,(f16)a.z,(f16)a.w,(f16)b.x,(f16)b.y,(f16)b.z,(f16)b.w};
    }
    const int gcol = cb * 128 + wid * 32 + lm;
    const float b2v0 = b_ih2[gcol] + b_hh2[gcol];
    const float b2v1 = b_ih2[gcol + 16] + b_hh2[gcol + 16];
    __syncthreads();

    int* myf = FLG(80 + bg * 16 + set * 4 + cb);
    const int* fH1 = FLG(bg);
    const int* fH2 = FLG(8 + bg);
    const int srow = tid >> 4;             // dest row (16 rows x 16 thr)
    const int soff = (tid & 15) * 32;      // dest col base within row
    int dead = 0;
    f16x8 R0, R1, R2, R3;
    {
      int v = 0, sp = 0;
      do { v = ldflag(fH1); if (v >= set + 1) break;
           __builtin_amdgcn_s_sleep(8); } while (++sp < SPINMAX);
      if (v < set + 1) dead = 1;
      const f16* hs = h1r + ((size_t)(set & 15) * 8 + bg) * 8192 + (size_t)tid * 32;
      R0 = ld128cc(hs); R1 = ld128cc(hs + 8); R2 = ld128cc(hs + 16); R3 = ld128cc(hs + 24);
    }
    int rH1 = ldflag(fH1), rH2 = ldflag(fH2);

    for (int q = set; q < Tt && !dead; q += 4) {
      VMFENCE();                                // R arrived; old par stores drained
      *(f16x8*)&sA[srow * 520 + soff]      = R0;
      *(f16x8*)&sA[srow * 520 + soff + 8]  = R1;
      *(f16x8*)&sA[srow * 520 + soff + 16] = R2;
      *(f16x8*)&sA[srow * 520 + soff + 24] = R3;
      __syncthreads();
      f32x4 acc0 = {b2v0, b2v0, b2v0, b2v0};
      f32x4 acc1 = {b2v1, b2v1, b2v1, b2v1};
      #pragma unroll
      for (int kc = 0; kc < 16; ++kc) {
        f16x8 A = *(const f16x8*)&sA[lm * 520 + kc * 32 + lk8];
        acc0 = mfma16(A, *(const f16x8*)&sW[((size_t)(kc * 4 + lgrp) * 128 + wid * 32 + lm) * 8], acc0);
        acc1 = mfma16(A, *(const f16x8*)&sW[((size_t)(kc * 4 + lgrp) * 128 + wid * 32 + 16 + lm) * 8], acc1);
      }
      f16* dst = parr + ((size_t)(q & 15) * 8 + bg) * 8192;
      st64cc(dst + (cb * 8 + wid * 2 + 0) * 256 + lm * 16 + lgrp * 4,
             f16x4{(f16)acc0[0], (f16)acc0[1], (f16)acc0[2], (f16)acc0[3]});
      st64cc(dst + (cb * 8 + wid * 2 + 1) * 256 + lm * 16 + lgrp * 4,
             f16x4{(f16)acc1[0], (f16)acc1[1], (f16)acc1[2], (f16)acc1[3]});
      VMFENCE();
      if (tid == 0) stflag(myf, q + 1);
      const int nq = q + 4;
      if (nq < Tt) {
        int haveR = 0;
        if (rH1 >= nq + 1) {
          const f16* hs = h1r + ((size_t)(nq & 15) * 8 + bg) * 8192 + (size_t)tid * 32;
          R0 = ld128cc(hs); R1 = ld128cc(hs + 8); R2 = ld128cc(hs + 16); R3 = ld128cc(hs + 24);
          haveR = 1;
        }
        if (nq >= 16 && rH2 < nq - 15) {
          int v = 0, sp = 0;
          do { v = ldflag(fH2); if (v >= nq - 15) break;
               __builtin_amdgcn_s_sleep(4); } while (++sp < SPINMAX);
          if (v < nq - 15) dead = 1;
        }
        if (!haveR && !dead) {
          int v = 0, sp = 0;
          do { v = ldflag(fH1); if (v >= nq + 1) break;
               __builtin_amdgcn_s_sleep(4); } while (++sp < SPINMAX);
          if (v < nq + 1) dead = 1;
          const f16* hs = h1r + ((size_t)(nq & 15) * 8 + bg) * 8192 + (size_t)tid * 32;
          R0 = ld128cc(hs); R1 = ld128cc(hs + 8); R2 = ld128cc(hs + 16); R3 = ld128cc(hs + 24);
        }
      }
      rH1 = ldflag(fH1); rH2 = ldflag(fH2);
      __syncthreads();
    }
    VMFENCE();
    if (tid == 0) stflag(myf, Tt + 2);
  } else {
    // ============ XW (144..207): xw_t = x_t @ w_ih1^T + b1 (4 sets x 2 halves) ============
    const int idx = bid - 144;
    const int bg = idx >> 3, r8 = idx & 7;
    const int set = r8 >> 1, half = r8 & 1;
    f16* sW = (f16*)LS;                    // [8kc][4grp][256col][8] (128KB)

    for (int i = tid; i < 8192; i += 256) {
      const int kc = i >> 10, grp = (i >> 8) & 3, cl = i & 255;
      const float* sp = w_ih1 + (size_t)(half * 256 + cl) * 256 + kc * 32 + grp * 8;
      float4 a = *(const float4*)sp, b = *(const float4*)(sp + 4);
      *(f16x8*)&sW[(size_t)i * 8] =
        f16x8{(f16)a.x,(f16)a.y,(f16)a.z,(f16)a.w,(f16)b.x,(f16)b.y,(f16)b.z,(f16)b.w};
    }
    const int gc0 = half * 256 + wid * 64 + lm;
    float b1v[4];
    #pragma unroll
    for (int nt = 0; nt < 4; ++nt)
      b1v[nt] = b_ih1[gc0 + nt * 16] + b_hh1[gc0 + nt * 16];
    __syncthreads();

    int* myf = FLG(16 + bg * 8 + set * 2 + half);
    const int* fH1 = FLG(bg);
    int rH1 = 0, dead = 0;
    for (int t = set; t < Tt && !dead; t += 4) {
      if (t >= 16 && rH1 < t - 15) {
        int v = 0, sp = 0;
        do { v = ldflag(fH1); if (v >= t - 15) break;
             __builtin_amdgcn_s_sleep(4); } while (++sp < SPINMAX);
        if (v < t - 15) dead = 1;
      }
      f32x4 acc[4];
      #pragma unroll
      for (int nt = 0; nt < 4; ++nt) acc[nt] = f32x4{b1v[nt], b1v[nt], b1v[nt], b1v[nt]};
      const float* xr = x + ((size_t)(bg * 16 + lm) * Tt + t) * Ii + lk8;
      #pragma unroll
      for (int kc = 0; kc < 8; ++kc) {
        float4 a = *(const float4*)(xr + kc * 32);
        float4 b = *(const float4*)(xr + kc * 32 + 4);
        f16x8 A{(f16)a.x,(f16)a.y,(f16)a.z,(f16)a.w,(f16)b.x,(f16)b.y,(f16)b.z,(f16)b.w};
        #pragma unroll
        for (int nt = 0; nt < 4; ++nt)
          acc[nt] = mfma16(A, *(const f16x8*)&sW[((size_t)(kc*4+lgrp)*256 + wid*64 + nt*16 + lm)*8], acc[nt]);
      }
      f16* dst = xwr + ((size_t)(t & 15) * 8 + bg) * 8192;
      #pragma unroll
      for (int nt = 0; nt < 4; ++nt)
        st64cc(dst + (half * 16 + wid * 4 + nt) * 256 + lm * 16 + lgrp * 4,
               f16x4{(f16)acc[nt][0], (f16)acc[nt][1], (f16)acc[nt][2], (f16)acc[nt][3]});
      VMFENCE();
      if (tid == 0) stflag(myf, t + 1);
      rH1 = ldflag(fH1);
    }
    if (tid == 0) stflag(myf, Tt + 2);
  }
}

extern "C" void kernel_launch(void* const* d_in, const int* in_sizes, int n_in,
                              void* d_out, int out_size, void* d_ws, size_t ws_size,
                              hipStream_t stream) {
  (void)in_sizes; (void)n_in; (void)out_size; (void)ws_size;
  const float* x     = (const float*)d_in[0];
  const float* w_ih1 = (const float*)d_in[1];
  const float* w_hh1 = (const float*)d_in[2];
  const float* b_ih1 = (const float*)d_in[3];
  const float* b_hh1 = (const float*)d_in[4];
  const float* w_ih2 = (const float*)d_in[5];
  const float* w_hh2 = (const float*)d_in[6];
  const float* b_ih2 = (const float*)d_in[7];
  const float* b_hh2 = (const float*)d_in[8];
  const float* w_out = (const float*)d_in[9];
  const float* b_out = (const float*)d_in[10];
  float* out = (float*)d_out;
  char* ws = (char*)d_ws;

  hipMemsetAsync(ws, 0, 32768, stream);
  hipLaunchKernelGGL(prep_weights, dim3(512), dim3(512), 0, stream, w_hh1, w_hh2, ws);
  hipLaunchKernelGGL(rnn_main, dim3(208), dim3(256), 0, stream,
                     x, w_ih1, w_ih2, b_ih1, b_hh1, b_ih2, b_hh2,
                     w_out, b_out, out, ws);
}

// Round 12
// 9623.557 us; speedup vs baseline: 1.4107x; 1.4107x over previous
//
#include <hip/hip_runtime.h>
#include <hip/hip_fp16.h>

#define Tt 1024
#define Ii 256
#define Hh 512
#define Cc 10
#define SPINMAX (1 << 27)

typedef _Float16 f16;
typedef _Float16 f16x8 __attribute__((ext_vector_type(8)));
typedef _Float16 f16x4 __attribute__((ext_vector_type(4)));
typedef _Float16 f16x2 __attribute__((ext_vector_type(2)));
typedef float    f32x4 __attribute__((ext_vector_type(4)));

// ---- ws byte offsets ----
#define OFF_FLAGS 0u        // ints: f_h1[8]@0, f_h2[8]@16, f_xw[8][2][2]@32, f_2a[8][3][4]@96
#define OFF_WH1   4096u     // f16 [512][512] w_hh1
#define OFF_WH2   528384u   // f16 [512][512] w_hh2
#define OFF_XWR   1052672u  // f16 [16 slot][8 bg][8192] frag-major (2 MB)
#define OFF_H1R   3149824u  // f16 [8 slot][8 bg][16*512] row-major (1 MB)
#define OFF_PAR   4198400u  // f16 [8 slot][8 bg][8192] frag-major (1 MB)

static __device__ __forceinline__ f32x4 mfma16(f16x8 a, f16x8 b, f32x4 c) {
  return __builtin_amdgcn_mfma_f32_16x16x32_f16(a, b, c, 0, 0, 0);
}
static __device__ __forceinline__ float fast_tanh(float v) {
  float e = __expf(2.0f * v);
  return 1.0f - 2.0f / (e + 1.0f);
}
static __device__ __forceinline__ int ldflag(const int* p) {
  return __hip_atomic_load(p, __ATOMIC_RELAXED, __HIP_MEMORY_SCOPE_AGENT);
}
static __device__ __forceinline__ void stflag(int* p, int v) {
  __hip_atomic_store(p, v, __ATOMIC_RELAXED, __HIP_MEMORY_SCOPE_AGENT);
}
static __device__ __forceinline__ f16x4 ld64cc(const f16* p) {
  union { unsigned long long u; f16x4 v; } U;
  U.u = __hip_atomic_load((const unsigned long long*)p, __ATOMIC_RELAXED, __HIP_MEMORY_SCOPE_AGENT);
  return U.v;
}
static __device__ __forceinline__ void st64cc(f16* p, f16x4 v) {
  union { unsigned long long u; f16x4 v; } U; U.v = v;
  __hip_atomic_store((unsigned long long*)p, U.u, __ATOMIC_RELAXED, __HIP_MEMORY_SCOPE_AGENT);
}
static __device__ __forceinline__ f16x8 ld128cc(const f16* p) {
  union { unsigned long long u[2]; f16x8 v; } U;
  U.u[0] = __hip_atomic_load((const unsigned long long*)p,     __ATOMIC_RELAXED, __HIP_MEMORY_SCOPE_AGENT);
  U.u[1] = __hip_atomic_load((const unsigned long long*)p + 1, __ATOMIC_RELAXED, __HIP_MEMORY_SCOPE_AGENT);
  return U.v;
}
static __device__ __forceinline__ void stu32cc(unsigned* p, unsigned v) {
  __hip_atomic_store(p, v, __ATOMIC_RELAXED, __HIP_MEMORY_SCOPE_AGENT);
}
static __device__ __forceinline__ int imin(int a, int b) { return a < b ? a : b; }

#define CFENCE() asm volatile("" ::: "memory")
#define VMFENCE() asm volatile("s_waitcnt vmcnt(0)" ::: "memory")
#define LBAR() do { asm volatile("s_waitcnt lgkmcnt(0)" ::: "memory"); \
                    __builtin_amdgcn_s_barrier(); \
                    __builtin_amdgcn_sched_barrier(0); } while (0)

// ---------- prologue kernel: w_hh1/w_hh2 fp32 -> f16 row-major ----------
__global__ void prep_weights(const float* __restrict__ w_hh1,
                             const float* __restrict__ w_hh2,
                             char* __restrict__ ws) {
  f16* wh1 = (f16*)(ws + OFF_WH1);
  f16* wh2 = (f16*)(ws + OFF_WH2);
  int i = blockIdx.x * 512 + threadIdx.x;
  if (i < 512 * 512) { wh1[i] = (f16)w_hh1[i]; wh2[i] = (f16)w_hh2[i]; }
}

// ---------- main persistent kernel ----------
__global__ __launch_bounds__(512, 1) void rnn_main(
    const float* __restrict__ x,
    const float* __restrict__ w_ih1, const float* __restrict__ w_ih2,
    const float* __restrict__ b_ih1, const float* __restrict__ b_hh1,
    const float* __restrict__ b_ih2, const float* __restrict__ b_hh2,
    const float* __restrict__ w_out, const float* __restrict__ b_out,
    float* __restrict__ out, char* __restrict__ ws)
{
  __shared__ __align__(16) char LS[147712];

  int* FL = (int*)(ws + OFF_FLAGS);
  const f16* wh1f = (const f16*)(ws + OFF_WH1);
  const f16* wh2f = (const f16*)(ws + OFF_WH2);
  f16* xwr = (f16*)(ws + OFF_XWR);
  f16* h1r = (f16*)(ws + OFF_H1R);
  f16* parr = (f16*)(ws + OFF_PAR);

  const int bid  = blockIdx.x;
  const int tid  = threadIdx.x;
  const int wid  = tid >> 6;
  const int lane = tid & 63;
  const int lm   = lane & 15;
  const int lgrp = lane >> 4;
  const int lk8  = lgrp * 8;
  const int rlo  = (lane & 1) * 2;

  if (bid < 16) {
    // ================== H1 (bid 0..7) / H2 (bid 8..15) ==================
    const bool isH1 = (bid < 8);
    const int bg = bid & 7;
    f16* sB = (f16*)LS;                 // [4 kc][4 grp][512 col][8] = 128 KB
    f16* sH = (f16*)(LS + 131072);      // [16][520] state
    unsigned* sH32 = (unsigned*)sH;
    const f16* whh = isH1 ? wh1f : wh2f;
    const int wcol0 = wid * 64;

    // stage sB: kc 0..3 of whh, frag layout
    for (int i = tid; i < 8192; i += 512) {
      const int kc = i >> 11, grp = (i >> 9) & 3, col = i & 511;
      f16x8 v = *(const f16x8*)&whh[col * 512 + kc * 32 + grp * 8];
      *(f16x8*)&sB[(size_t)i * 8] = v;
    }
    for (int i = tid; i < 16 * 260; i += 512) sH32[i] = 0u;
    // kc 4..11 pinned into AGPRs (128/lane): "+a" makes them opaque (no remat)
    f16x8 wbA[8][4];
    #pragma unroll
    for (int kr = 0; kr < 8; ++kr) {
      #pragma unroll
      for (int nt = 0; nt < 4; ++nt) {
        wbA[kr][nt] = *(const f16x8*)&whh[(size_t)(wcol0 + nt * 16 + lm) * 512 + (kr + 4) * 32 + lk8];
        asm volatile("" : "+a"(wbA[kr][nt]));
      }
    }
    __syncthreads();

    int fA_cur = -1;   // H1: min xw-pair; H2: min 2a-quad for current step
    int fG_cur = -1;   // H1: min 2a-quad (ring guard); H2: unused
    const int T = Tt;

    for (int p = 0; p < T; ++p) {
      // ---- 1. flag checks (prefetched; spin with bail only if behind) ----
      if (isH1) {
        if (fA_cur < p + 1) {
          const int* pa = FL + 32 + (bg * 2 + (p & 1)) * 2;
          int s = 0, a, b;
          do { a = ldflag(pa); b = ldflag(pa + 1); if (++s > SPINMAX) break; }
          while (imin(a, b) < p + 1);
        }
        if (p >= 8 && fG_cur < p - 7) {
          const int sg = (p - 8) % 3;
          const int* qa = FL + 96 + (bg * 3 + sg) * 4;
          int s = 0, m;
          do { m = imin(imin(ldflag(qa), ldflag(qa + 1)), imin(ldflag(qa + 2), ldflag(qa + 3)));
               if (++s > SPINMAX) break; } while (m < p - 7);
        }
      } else {
        if (fA_cur < p + 1) {
          const int sg = p % 3;
          const int* qa = FL + 96 + (bg * 3 + sg) * 4;
          int s = 0, m;
          do { m = imin(imin(ldflag(qa), ldflag(qa + 1)), imin(ldflag(qa + 2), ldflag(qa + 3)));
               if (++s > SPINMAX) break; } while (m < p + 1);
        }
      }
      CFENCE();

      // ---- 2. issue feed-in loads (xw_p or par_p), frag-major ----
      const f16* fin = isH1 ? (xwr + ((size_t)(p & 15) * 8 + bg) * 8192)
                            : (parr + ((size_t)(p & 7) * 8 + bg) * 8192);
      f16x4 xv[4];
      #pragma unroll
      for (int nt = 0; nt < 4; ++nt)
        xv[nt] = ld64cc(fin + (wid * 4 + nt) * 256 + lm * 16 + lgrp * 4);

      // ---- 3. MFMA phase: B = sB(kc0-3) + AGPR(kc4-11) + staggered L2 stream(kc12-15) ----
      f32x4 acc[4];
      #pragma unroll
      for (int nt = 0; nt < 4; ++nt) acc[nt] = f32x4{0.f, 0.f, 0.f, 0.f};
      if (p > 0) {
        f16x8 ws[4][4];
        #pragma unroll
        for (int g = 0; g < 2; ++g)
          #pragma unroll
          for (int nt = 0; nt < 4; ++nt)
            ws[g][nt] = *(const f16x8*)&whh[(size_t)(wcol0 + nt * 16 + lm) * 512 + (12 + g) * 32 + lk8];
        #pragma unroll
        for (int kc = 0; kc < 16; ++kc) {
          if (kc == 8) {
            #pragma unroll
            for (int g = 2; g < 4; ++g)
              #pragma unroll
              for (int nt = 0; nt < 4; ++nt)
                ws[g][nt] = *(const f16x8*)&whh[(size_t)(wcol0 + nt * 16 + lm) * 512 + (12 + g) * 32 + lk8];
          }
          f16x8 A = *(const f16x8*)&sH[lm * 520 + kc * 32 + lk8];
          #pragma unroll
          for (int nt = 0; nt < 4; ++nt) {
            f16x8 B;
            if (kc < 4)       B = *(const f16x8*)&sB[((size_t)(kc * 4 + lgrp) * 512 + wcol0 + nt * 16 + lm) * 8];
            else if (kc < 12) B = wbA[kc - 4][nt];
            else              B = ws[kc - 12][nt];
            acc[nt] = mfma16(A, B, acc[nt]);
          }
        }
      }
      // barrier A: all state reads done before state overwrite
      LBAR();

      // ---- 4. add feed-in ----
      #pragma unroll
      for (int nt = 0; nt < 4; ++nt) {
        #pragma unroll
        for (int r = 0; r < 4; ++r) acc[nt][r] += (float)xv[nt][r];
      }

      // ---- 5. periodic publish (stores of step p-1 are a period old: drain ~free) ----
      if ((p & 3) == 0 && p > 0) {
        VMFENCE();
        if (tid == 0) stflag(FL + (isH1 ? 0 : 16) + bg, p);
      }

      // ---- 6. tanh + epi: write sH (ds) and (H1 only) h1 ring (sc1) ----
      unsigned* ring32 = (unsigned*)(h1r + ((size_t)(p & 7) * 8 + bg) * 8192);
      #pragma unroll
      for (int nt = 0; nt < 4; ++nt) {
        const int cp = (wcol0 + nt * 16 + lm) >> 1;
        float v0 = fast_tanh(acc[nt][0]), v1 = fast_tanh(acc[nt][1]);
        float v2 = fast_tanh(acc[nt][2]), v3 = fast_tanh(acc[nt][3]);
        float o0 = __shfl_xor(v0, 1, 64), o1 = __shfl_xor(v1, 1, 64);
        float o2 = __shfl_xor(v2, 1, 64), o3 = __shfl_xor(v3, 1, 64);
        float m[4] = {v0, v1, v2, v3}, q[4] = {o0, o1, o2, o3};
        #pragma unroll
        for (int r2 = 0; r2 < 2; ++r2) {
          const int rr = rlo + r2, row = lgrp * 4 + rr;
          float ve = (lane & 1) ? q[rr] : m[rr];
          float vo = (lane & 1) ? m[rr] : q[rr];
          union { f16x2 h; unsigned u; } P; P.h = f16x2{(f16)ve, (f16)vo};
          sH32[row * 260 + cp] = P.u;
          if (isH1) stu32cc(ring32 + row * 256 + cp, P.u);
        }
      }

      // ---- 7. prefetch flags for p+1 (consumed next iteration) ----
      if (isH1) {
        const int* pa = FL + 32 + (bg * 2 + ((p + 1) & 1)) * 2;
        fA_cur = imin(ldflag(pa), ldflag(pa + 1));
        const int sg2 = (p + 1 >= 8) ? ((p - 7) % 3) : 0;
        const int* qa = FL + 96 + (bg * 3 + sg2) * 4;
        fG_cur = imin(imin(ldflag(qa), ldflag(qa + 1)), imin(ldflag(qa + 2), ldflag(qa + 3)));
      } else {
        const int sg2 = (p + 1) % 3;
        const int* qa = FL + 96 + (bg * 3 + sg2) * 4;
        fA_cur = imin(imin(ldflag(qa), ldflag(qa + 1)), imin(ldflag(qa + 2), ldflag(qa + 3)));
      }

      // barrier B: state writes visible before next step's reads
      LBAR();
    }

    // final publish
    VMFENCE();
    if (tid == 0) stflag(FL + (isH1 ? 0 : 16) + bg, Tt);
    if (tid == 0 && isH1) stflag(FL + bg, Tt + 1);
    if (tid == 0 && !isH1) stflag(FL + 16 + bg, Tt + 1);

    // ---- H2: final output  out = h2_{T-1} @ w_out^T + b_out ----
    if (!isH1) {
      const int rl = wid * 2 + (lane >> 5);
      const int l32 = lane & 31;
      const f16* hr = &sH[rl * 520 + l32 * 16];
      f16x8 h0 = *(const f16x8*)hr;
      f16x8 h1v = *(const f16x8*)(hr + 8);
      float hf[16];
      #pragma unroll
      for (int j = 0; j < 8; ++j) { hf[j] = (float)h0[j]; hf[8 + j] = (float)h1v[j]; }
      #pragma unroll
      for (int c = 0; c < Cc; ++c) {
        const float* wr_ = w_out + (size_t)c * Hh + l32 * 16;
        float s = 0.f;
        #pragma unroll
        for (int j4 = 0; j4 < 4; ++j4) {
          float4 w4 = *(const float4*)(wr_ + j4 * 4);
          s += hf[j4*4]*w4.x + hf[j4*4+1]*w4.y + hf[j4*4+2]*w4.z + hf[j4*4+3]*w4.w;
        }
        #pragma unroll
        for (int off = 16; off >= 1; off >>= 1) s += __shfl_xor(s, off, 64);
        if (l32 == 0) out[(bg * 16 + rl) * Cc + c] = s + b_out[c];
      }
    }
  } else if (bid < 112) {
    // ================== 2A (bid 16..111): par = h1 @ w_ih2^T + b2 ==================
    const int idx = bid - 16;
    const int bg = idx / 12, r = idx % 12;
    const int set = r >> 2, cb = r & 3;
    f16* sW = (f16*)LS;                 // [16 kc][4 grp][128 col][8] = 128 KB
    f16* sA = (f16*)(LS + 131072);      // staged h1 [16][520]

    for (int i = tid; i < 8192; i += 512) {
      const int kc = i >> 9, grp = (i >> 7) & 3, cl = i & 127;
      const float* sp = w_ih2 + (size_t)(cb * 128 + cl) * 512 + kc * 32 + grp * 8;
      float4 a = *(const float4*)sp, b = *(const float4*)(sp + 4);
      f16x8 v{(f16)a.x,(f16)a.y,(f16)a.z,(f16)a.w,(f16)b.x,(f16)b.y,(f16)b.z,(f16)b.w};
      *(f16x8*)&sW[(size_t)i * 8] = v;
    }
    const int gcol = cb * 128 + wid * 16 + lm;
    const float bias2v = b_ih2[gcol] + b_hh2[gcol];
    __syncthreads();

    for (int q = set; q < Tt; q += 3) {
      if (q >= 8) {             // par ring overwrite guard
        int s = 0;
        while (ldflag(FL + 16 + bg) < q - 7) { if (++s > SPINMAX) break; __builtin_amdgcn_s_sleep(1); }
      }
      { int s = 0;              // wait h1_q visible
        while (ldflag(FL + bg) < q + 1) { if (++s > SPINMAX) break; __builtin_amdgcn_s_sleep(1); } }
      CFENCE();
      // stage h1_q slice into LDS (padded rows)
      const f16* hsrc = h1r + ((size_t)(q & 7) * 8 + bg) * 8192;
      #pragma unroll
      for (int c = 0; c < 2; ++c) {
        const int ch = tid * 2 + c;
        const int row = ch >> 6, c16 = ch & 63;
        f16x8 v = ld128cc(hsrc + ch * 8);
        *(f16x8*)&sA[row * 520 + c16 * 8] = v;
      }
      __syncthreads();
      f32x4 acc = {bias2v, bias2v, bias2v, bias2v};
      #pragma unroll
      for (int kc = 0; kc < 16; ++kc) {
        f16x8 A = *(const f16x8*)&sA[lm * 520 + kc * 32 + lk8];
        f16x8 B = *(const f16x8*)&sW[((size_t)(kc * 4 + lgrp) * 128 + wid * 16 + lm) * 8];
        acc = mfma16(A, B, acc);
      }
      f16x4 pv{(f16)acc[0], (f16)acc[1], (f16)acc[2], (f16)acc[3]};
      st64cc(parr + ((size_t)(q & 7) * 8 + bg) * 8192 + (cb * 8 + wid) * 256 + lm * 16 + lgrp * 4, pv);
      VMFENCE();
      if (tid == 0) stflag(FL + 96 + (bg * 3 + set) * 4 + cb, q + 1);
      __syncthreads();
    }
  } else {
    // ================== XW (bid 112..143): xw = x_t @ w_ih1^T + b1 ==================
    const int idx = bid - 112;
    const int bg = idx >> 2, r = idx & 3;
    const int set = r >> 1, half = r & 1;
    f16* sW = (f16*)LS;                 // [8 kc][4 grp][256 col][8] = 128 KB

    for (int i = tid; i < 8192; i += 512) {
      const int kc = i >> 10, grp = (i >> 8) & 3, cl = i & 255;
      const float* sp = w_ih1 + (size_t)(half * 256 + cl) * 256 + kc * 32 + grp * 8;
      float4 a = *(const float4*)sp, b = *(const float4*)(sp + 4);
      f16x8 v{(f16)a.x,(f16)a.y,(f16)a.z,(f16)a.w,(f16)b.x,(f16)b.y,(f16)b.z,(f16)b.w};
      *(f16x8*)&sW[(size_t)i * 8] = v;
    }
    const int gc0 = half * 256 + wid * 32 + lm;
    const float b1v0 = b_ih1[gc0] + b_hh1[gc0];
    const float b1v1 = b_ih1[gc0 + 16] + b_hh1[gc0 + 16];
    __syncthreads();

    for (int t = set; t < Tt; t += 2) {
      if (t >= 16) {            // xw ring overwrite guard
        int s = 0;
        while (ldflag(FL + bg) < t - 15) { if (++s > SPINMAX) break; __builtin_amdgcn_s_sleep(1); }
      }
      CFENCE();
      f32x4 acc0 = {b1v0, b1v0, b1v0, b1v0};
      f32x4 acc1 = {b1v1, b1v1, b1v1, b1v1};
      const float* xr = x + ((size_t)(bg * 16 + lm) * Tt + t) * Ii + lk8;
      #pragma unroll
      for (int kc = 0; kc < 8; ++kc) {
        float4 a = *(const float4*)(xr + kc * 32);
        float4 b = *(const float4*)(xr + kc * 32 + 4);
        f16x8 A{(f16)a.x,(f16)a.y,(f16)a.z,(f16)a.w,(f16)b.x,(f16)b.y,(f16)b.z,(f16)b.w};
        acc0 = mfma16(A, *(const f16x8*)&sW[((size_t)(kc * 4 + lgrp) * 256 + wid * 32 + lm) * 8], acc0);
        acc1 = mfma16(A, *(const f16x8*)&sW[((size_t)(kc * 4 + lgrp) * 256 + wid * 32 + 16 + lm) * 8], acc1);
      }
      f16* dst = xwr + ((size_t)(t & 15) * 8 + bg) * 8192;
      f16x4 p0{(f16)acc0[0], (f16)acc0[1], (f16)acc0[2], (f16)acc0[3]};
      f16x4 p1{(f16)acc1[0], (f16)acc1[1], (f16)acc1[2], (f16)acc1[3]};
      st64cc(dst + (half * 16 + wid * 2 + 0) * 256 + lm * 16 + lgrp * 4, p0);
      st64cc(dst + (half * 16 + wid * 2 + 1) * 256 + lm * 16 + lgrp * 4, p1);
      VMFENCE();
      if (tid == 0) stflag(FL + 32 + (bg * 2 + set) * 2 + half, t + 1);
    }
  }
}

extern "C" void kernel_launch(void* const* d_in, const int* in_sizes, int n_in,
                              void* d_out, int out_size, void* d_ws, size_t ws_size,
                              hipStream_t stream) {
  (void)in_sizes; (void)n_in; (void)out_size; (void)ws_size;
  const float* x     = (const float*)d_in[0];
  const float* w_ih1 = (const float*)d_in[1];
  const float* w_hh1 = (const float*)d_in[2];
  const float* b_ih1 = (const float*)d_in[3];
  const float* b_hh1 = (const float*)d_in[4];
  const float* w_ih2 = (const float*)d_in[5];
  const float* w_hh2 = (const float*)d_in[6];
  const float* b_ih2 = (const float*)d_in[7];
  const float* b_hh2 = (const float*)d_in[8];
  const float* w_out = (const float*)d_in[9];
  const float* b_out = (const float*)d_in[10];
  float* out = (float*)d_out;
  char* ws = (char*)d_ws;

  hipMemsetAsync(ws, 0, 4096, stream);   // flags
  hipLaunchKernelGGL(prep_weights, dim3(512), dim3(512), 0, stream, w_hh1, w_hh2, ws);
  hipLaunchKernelGGL(rnn_main, dim3(144), dim3(512), 0, stream,
                     x, w_ih1, w_ih2, b_ih1, b_hh1, b_ih2, b_hh2,
                     w_out, b_out, out, ws);
}

// Round 13
// 8115.416 us; speedup vs baseline: 1.6728x; 1.1858x over previous
//
#include <hip/hip_runtime.h>
#include <hip/hip_fp16.h>

#define Tt 1024
#define Ii 256
#define Hh 512
#define Cc 10
#define SPINMAX (1 << 27)

typedef _Float16 f16;
typedef _Float16 f16x8 __attribute__((ext_vector_type(8)));
typedef _Float16 f16x4 __attribute__((ext_vector_type(4)));
typedef _Float16 f16x2 __attribute__((ext_vector_type(2)));
typedef float    f32x4 __attribute__((ext_vector_type(4)));

// ---- ws byte offsets ----
#define OFF_FLAGS 0u        // ints: f_h1[8]@0, f_h2[8]@16, f_xw[8][2][2]@32, f_2a[8][3][4]@96
#define OFF_WH1   4096u     // f16 [512][512] w_hh1
#define OFF_WH2   528384u   // f16 [512][512] w_hh2
#define OFF_XWR   1052672u  // f16 [16 slot][8 bg][8192] frag-major (2 MB)
#define OFF_H1R   3149824u  // f16 [16 slot][8 bg][16*512] row-major (2 MB)
#define OFF_PAR   5246976u  // f16 [16 slot][8 bg][8192] frag-major (2 MB)

static __device__ __forceinline__ f32x4 mfma16(f16x8 a, f16x8 b, f32x4 c) {
  return __builtin_amdgcn_mfma_f32_16x16x32_f16(a, b, c, 0, 0, 0);
}
static __device__ __forceinline__ float fast_tanh(float v) {
  float e = __expf(2.0f * v);
  return 1.0f - 2.0f / (e + 1.0f);
}
static __device__ __forceinline__ int ldflag(const int* p) {
  return __hip_atomic_load(p, __ATOMIC_RELAXED, __HIP_MEMORY_SCOPE_AGENT);
}
static __device__ __forceinline__ void stflag(int* p, int v) {
  __hip_atomic_store(p, v, __ATOMIC_RELAXED, __HIP_MEMORY_SCOPE_AGENT);
}
static __device__ __forceinline__ f16x4 ld64cc(const f16* p) {
  union { unsigned long long u; f16x4 v; } U;
  U.u = __hip_atomic_load((const unsigned long long*)p, __ATOMIC_RELAXED, __HIP_MEMORY_SCOPE_AGENT);
  return U.v;
}
static __device__ __forceinline__ void st64cc(f16* p, f16x4 v) {
  union { unsigned long long u; f16x4 v; } U; U.v = v;
  __hip_atomic_store((unsigned long long*)p, U.u, __ATOMIC_RELAXED, __HIP_MEMORY_SCOPE_AGENT);
}
static __device__ __forceinline__ f16x8 ld128cc(const f16* p) {
  union { unsigned long long u[2]; f16x8 v; } U;
  U.u[0] = __hip_atomic_load((const unsigned long long*)p,     __ATOMIC_RELAXED, __HIP_MEMORY_SCOPE_AGENT);
  U.u[1] = __hip_atomic_load((const unsigned long long*)p + 1, __ATOMIC_RELAXED, __HIP_MEMORY_SCOPE_AGENT);
  return U.v;
}
static __device__ __forceinline__ void stu32cc(unsigned* p, unsigned v) {
  __hip_atomic_store(p, v, __ATOMIC_RELAXED, __HIP_MEMORY_SCOPE_AGENT);
}
static __device__ __forceinline__ int imin(int a, int b) { return a < b ? a : b; }

#define CFENCE() asm volatile("" ::: "memory")
#define VMFENCE() asm volatile("s_waitcnt vmcnt(0)" ::: "memory")
#define LBAR() do { asm volatile("s_waitcnt lgkmcnt(0)" ::: "memory"); \
                    __builtin_amdgcn_s_barrier(); \
                    __builtin_amdgcn_sched_barrier(0); } while (0)

// ---------- prologue kernel: w_hh1/w_hh2 fp32 -> f16 row-major ----------
__global__ void prep_weights(const float* __restrict__ w_hh1,
                             const float* __restrict__ w_hh2,
                             char* __restrict__ ws) {
  f16* wh1 = (f16*)(ws + OFF_WH1);
  f16* wh2 = (f16*)(ws + OFF_WH2);
  int i = blockIdx.x * 512 + threadIdx.x;
  if (i < 512 * 512) { wh1[i] = (f16)w_hh1[i]; wh2[i] = (f16)w_hh2[i]; }
}

// ---------- main persistent kernel ----------
__global__ __launch_bounds__(512, 1) void rnn_main(
    const float* __restrict__ x,
    const float* __restrict__ w_ih1, const float* __restrict__ w_ih2,
    const float* __restrict__ b_ih1, const float* __restrict__ b_hh1,
    const float* __restrict__ b_ih2, const float* __restrict__ b_hh2,
    const float* __restrict__ w_out, const float* __restrict__ b_out,
    float* __restrict__ out, char* __restrict__ ws)
{
  __shared__ __align__(16) char LS[147712];

  int* FL = (int*)(ws + OFF_FLAGS);
  const f16* wh1f = (const f16*)(ws + OFF_WH1);
  const f16* wh2f = (const f16*)(ws + OFF_WH2);
  f16* xwr = (f16*)(ws + OFF_XWR);
  f16* h1r = (f16*)(ws + OFF_H1R);
  f16* parr = (f16*)(ws + OFF_PAR);

  const int bid  = blockIdx.x;
  const int tid  = threadIdx.x;
  const int wid  = tid >> 6;
  const int lane = tid & 63;
  const int lm   = lane & 15;
  const int lgrp = lane >> 4;
  const int lk8  = lgrp * 8;
  const int rlo  = (lane & 1) * 2;

  if (bid < 16) {
    // ================== H1 (bid 0..7) / H2 (bid 8..15) ==================
    const bool isH1 = (bid < 8);
    const int bg = bid & 7;
    f16* sB = (f16*)LS;                 // [4 kc][4 grp][512 col][8] = 128 KB
    f16* sH = (f16*)(LS + 131072);      // [16][520] state
    unsigned* sH32 = (unsigned*)sH;
    const f16* whh = isH1 ? wh1f : wh2f;
    const int wcol0 = wid * 64;

    // stage sB: kc 0..3 of whh, frag layout
    for (int i = tid; i < 8192; i += 512) {
      const int kc = i >> 11, grp = (i >> 9) & 3, col = i & 511;
      f16x8 v = *(const f16x8*)&whh[col * 512 + kc * 32 + grp * 8];
      *(f16x8*)&sB[(size_t)i * 8] = v;
    }
    for (int i = tid; i < 16 * 260; i += 512) sH32[i] = 0u;
    // reg-B: kc 4..15 (compiler may stream these from L2 — that's the r7 baseline)
    f16x8 wb[12][4];
    #pragma unroll
    for (int kr = 0; kr < 12; ++kr)
      #pragma unroll
      for (int nt = 0; nt < 4; ++nt)
        wb[kr][nt] = *(const f16x8*)&whh[(size_t)(wcol0 + nt * 16 + lm) * 512 + (kr + 4) * 32 + lk8];
    __syncthreads();

    // raw flag registers (issued one step early; min computed at use)
    int rF0 = -1, rF1 = -1, rF2 = -1, rF3 = -1;   // feed flags
    int rG0 = -1, rG1 = -1, rG2 = -1, rG3 = -1;   // H1 ring guard flags

    for (int p = 0; p < Tt; ++p) {
      // ---- 1. checks using raws issued last step (slow-path spin if behind) ----
      if (isH1) {
        if (imin(rF0, rF1) < p + 1) {
          const int* pa = FL + 32 + (bg * 2 + (p & 1)) * 2;
          int s = 0, a, b;
          do { a = ldflag(pa); b = ldflag(pa + 1); if (++s > SPINMAX) break; }
          while (imin(a, b) < p + 1);
        }
        if (p >= 16 && imin(imin(rG0, rG1), imin(rG2, rG3)) < p - 15) {
          const int sg = (p - 16) % 3;
          const int* qa = FL + 96 + (bg * 3 + sg) * 4;
          int s = 0, m;
          do { m = imin(imin(ldflag(qa), ldflag(qa + 1)), imin(ldflag(qa + 2), ldflag(qa + 3)));
               if (++s > SPINMAX) break; } while (m < p - 15);
        }
      } else {
        if (imin(imin(rF0, rF1), imin(rF2, rF3)) < p + 1) {
          const int sg = p % 3;
          const int* qa = FL + 96 + (bg * 3 + sg) * 4;
          int s = 0, m;
          do { m = imin(imin(ldflag(qa), ldflag(qa + 1)), imin(ldflag(qa + 2), ldflag(qa + 3)));
               if (++s > SPINMAX) break; } while (m < p + 1);
        }
      }
      CFENCE();

      // ---- 2. issue feed-in loads (xw_p or par_p), frag-major ----
      const f16* fin = isH1 ? (xwr + ((size_t)(p & 15) * 8 + bg) * 8192)
                            : (parr + ((size_t)(p & 15) * 8 + bg) * 8192);
      f16x4 xv[4];
      #pragma unroll
      for (int nt = 0; nt < 4; ++nt)
        xv[nt] = ld64cc(fin + (wid * 4 + nt) * 256 + lm * 16 + lgrp * 4);

      // ---- 2.5 issue raw flag loads for step p+1 (consumed next iter: hidden) ----
      if (isH1) {
        const int* pa = FL + 32 + (bg * 2 + ((p + 1) & 1)) * 2;
        rF0 = ldflag(pa); rF1 = ldflag(pa + 1);
        if (p + 1 >= 16) {
          const int* qa = FL + 96 + (bg * 3 + ((p - 15) % 3)) * 4;
          rG0 = ldflag(qa); rG1 = ldflag(qa + 1);
          rG2 = ldflag(qa + 2); rG3 = ldflag(qa + 3);
        }
      } else {
        const int* qa = FL + 96 + (bg * 3 + ((p + 1) % 3)) * 4;
        rF0 = ldflag(qa); rF1 = ldflag(qa + 1);
        rF2 = ldflag(qa + 2); rF3 = ldflag(qa + 3);
      }

      // ---- 3. MFMA: A = h_{p-1} (LDS); B = sB(kc<4) + wb (kc>=4) ----
      f32x4 acc[4];
      #pragma unroll
      for (int nt = 0; nt < 4; ++nt) acc[nt] = f32x4{0.f, 0.f, 0.f, 0.f};
      if (p > 0) {
        #pragma unroll
        for (int kc = 0; kc < 16; ++kc) {
          f16x8 A = *(const f16x8*)&sH[lm * 520 + kc * 32 + lk8];
          if (kc < 4) {
            #pragma unroll
            for (int nt = 0; nt < 4; ++nt)
              acc[nt] = mfma16(A, *(const f16x8*)&sB[((size_t)(kc * 4 + lgrp) * 512 + wcol0 + nt * 16 + lm) * 8], acc[nt]);
          } else {
            #pragma unroll
            for (int nt = 0; nt < 4; ++nt)
              acc[nt] = mfma16(A, wb[kc - 4][nt], acc[nt]);
          }
        }
      }
      // barrier A: all state reads done before state overwrite
      LBAR();

      // ---- 4. add feed-in ----
      #pragma unroll
      for (int nt = 0; nt < 4; ++nt) {
        #pragma unroll
        for (int r = 0; r < 4; ++r) acc[nt][r] += (float)xv[nt][r];
      }

      // ---- 5. publish every 2 steps (only old stores outstanding: fence ~free) ----
      if ((p & 1) == 0 && p > 0) {
        VMFENCE();
        if (tid == 0) stflag(FL + (isH1 ? 0 : 16) + bg, p);
      }

      // ---- 6. tanh + epi: write sH (ds) and (H1 only) h1 ring (sc1) ----
      unsigned* ring32 = (unsigned*)(h1r + ((size_t)(p & 15) * 8 + bg) * 8192);
      #pragma unroll
      for (int nt = 0; nt < 4; ++nt) {
        const int cp = (wcol0 + nt * 16 + lm) >> 1;
        float v0 = fast_tanh(acc[nt][0]), v1 = fast_tanh(acc[nt][1]);
        float v2 = fast_tanh(acc[nt][2]), v3 = fast_tanh(acc[nt][3]);
        float o0 = __shfl_xor(v0, 1, 64), o1 = __shfl_xor(v1, 1, 64);
        float o2 = __shfl_xor(v2, 1, 64), o3 = __shfl_xor(v3, 1, 64);
        float m[4] = {v0, v1, v2, v3}, q[4] = {o0, o1, o2, o3};
        #pragma unroll
        for (int r2 = 0; r2 < 2; ++r2) {
          const int rr = rlo + r2, row = lgrp * 4 + rr;
          float ve = (lane & 1) ? q[rr] : m[rr];
          float vo = (lane & 1) ? m[rr] : q[rr];
          union { f16x2 h; unsigned u; } P; P.h = f16x2{(f16)ve, (f16)vo};
          sH32[row * 260 + cp] = P.u;
          if (isH1) stu32cc(ring32 + row * 256 + cp, P.u);
        }
      }

      // barrier B: state writes visible before next step's reads
      LBAR();
    }

    // final publish
    VMFENCE();
    if (tid == 0) stflag(FL + (isH1 ? 0 : 16) + bg, Tt + 2);

    // ---- H2: final output  out = h2_{T-1} @ w_out^T + b_out ----
    if (!isH1) {
      const int rl = wid * 2 + (lane >> 5);
      const int l32 = lane & 31;
      const f16* hr = &sH[rl * 520 + l32 * 16];
      f16x8 h0 = *(const f16x8*)hr;
      f16x8 h1v = *(const f16x8*)(hr + 8);
      float hf[16];
      #pragma unroll
      for (int j = 0; j < 8; ++j) { hf[j] = (float)h0[j]; hf[8 + j] = (float)h1v[j]; }
      #pragma unroll
      for (int c = 0; c < Cc; ++c) {
        const float* wr_ = w_out + (size_t)c * Hh + l32 * 16;
        float s = 0.f;
        #pragma unroll
        for (int j4 = 0; j4 < 4; ++j4) {
          float4 w4 = *(const float4*)(wr_ + j4 * 4);
          s += hf[j4*4]*w4.x + hf[j4*4+1]*w4.y + hf[j4*4+2]*w4.z + hf[j4*4+3]*w4.w;
        }
        #pragma unroll
        for (int off = 16; off >= 1; off >>= 1) s += __shfl_xor(s, off, 64);
        if (l32 == 0) out[(bg * 16 + rl) * Cc + c] = s + b_out[c];
      }
    }
  } else if (bid < 112) {
    // ================== 2A (bid 16..111): par = h1 @ w_ih2^T + b2 ==================
    const int idx = bid - 16;
    const int bg = idx / 12, r = idx % 12;
    const int set = r >> 2, cb = r & 3;
    f16* sW = (f16*)LS;                 // [16 kc][4 grp][128 col][8] = 128 KB
    f16* sA = (f16*)(LS + 131072);      // staged h1 [16][520]

    for (int i = tid; i < 8192; i += 512) {
      const int kc = i >> 9, grp = (i >> 7) & 3, cl = i & 127;
      const float* sp = w_ih2 + (size_t)(cb * 128 + cl) * 512 + kc * 32 + grp * 8;
      float4 a = *(const float4*)sp, b = *(const float4*)(sp + 4);
      f16x8 v{(f16)a.x,(f16)a.y,(f16)a.z,(f16)a.w,(f16)b.x,(f16)b.y,(f16)b.z,(f16)b.w};
      *(f16x8*)&sW[(size_t)i * 8] = v;
    }
    const int gcol = cb * 128 + wid * 16 + lm;
    const float bias2v = b_ih2[gcol] + b_hh2[gcol];
    __syncthreads();

    int* myf = FL + 96 + (bg * 3 + set) * 4 + cb;
    const int* fH1 = FL + bg;
    const int* fH2 = FL + 16 + bg;
    int dead = 0;
    f16x8 R0, R1;
    { // prologue: wait h1_set visible, issue R loads
      int s = 0;
      while (ldflag(fH1) < set + 1) { if (++s > SPINMAX) { dead = 1; break; } __builtin_amdgcn_s_sleep(1); }
      const f16* hs = h1r + ((size_t)(set & 15) * 8 + bg) * 8192;
      R0 = ld128cc(hs + (size_t)tid * 16);
      R1 = ld128cc(hs + (size_t)tid * 16 + 8);
    }
    int rH1 = ldflag(fH1), rH2 = ldflag(fH2);

    for (int q = set; q < Tt && !dead; q += 3) {
      VMFENCE();                                   // R arrived; old par store drained
      if (q >= 3 && tid == 0) stflag(myf, q - 2);  // certify par_{q-3} + h1_{q-3} read
      *(f16x8*)&sA[(tid >> 5) * 520 + (tid & 31) * 16]     = R0;
      *(f16x8*)&sA[(tid >> 5) * 520 + (tid & 31) * 16 + 8] = R1;
      __syncthreads();
      f32x4 acc = {bias2v, bias2v, bias2v, bias2v};
      #pragma unroll
      for (int kc = 0; kc < 16; ++kc) {
        f16x8 A = *(const f16x8*)&sA[lm * 520 + kc * 32 + lk8];
        f16x8 B = *(const f16x8*)&sW[((size_t)(kc * 4 + lgrp) * 128 + wid * 16 + lm) * 8];
        acc = mfma16(A, B, acc);
      }
      // par-ring overwrite guard (slot q&15 held par_{q-16}): need H2 done q-16
      if (q >= 16 && rH2 < q - 15) {
        int s = 0, v;
        do { v = ldflag(fH2); if (v >= q - 15) break;
             __builtin_amdgcn_s_sleep(1); } while (++s < SPINMAX);
        if (v < q - 15) dead = 1;
      }
      st64cc(parr + ((size_t)(q & 15) * 8 + bg) * 8192 + (cb * 8 + wid) * 256 + lm * 16 + lgrp * 4,
             f16x4{(f16)acc[0], (f16)acc[1], (f16)acc[2], (f16)acc[3]});
      // prefetch R for q+3 (needs h1 flag >= q+4; raw from last iter usually covers)
      if (q + 3 < Tt) {
        if (rH1 < q + 4) {
          int s = 0, v;
          do { v = ldflag(fH1); if (v >= q + 4) break;
               __builtin_amdgcn_s_sleep(1); } while (++s < SPINMAX);
          if (v < q + 4) dead = 1;
        }
        const f16* hs = h1r + ((size_t)((q + 3) & 15) * 8 + bg) * 8192;
        R0 = ld128cc(hs + (size_t)tid * 16);
        R1 = ld128cc(hs + (size_t)tid * 16 + 8);
      }
      rH1 = ldflag(fH1); rH2 = ldflag(fH2);
      __syncthreads();
    }
    VMFENCE();
    if (tid == 0) stflag(myf, Tt + 2);
  } else {
    // ================== XW (bid 112..143): xw = x_t @ w_ih1^T + b1 ==================
    const int idx = bid - 112;
    const int bg = idx >> 2, r = idx & 3;
    const int set = r >> 1, half = r & 1;
    f16* sW = (f16*)LS;                 // [8 kc][4 grp][256 col][8] = 128 KB

    for (int i = tid; i < 8192; i += 512) {
      const int kc = i >> 10, grp = (i >> 8) & 3, cl = i & 255;
      const float* sp = w_ih1 + (size_t)(half * 256 + cl) * 256 + kc * 32 + grp * 8;
      float4 a = *(const float4*)sp, b = *(const float4*)(sp + 4);
      f16x8 v{(f16)a.x,(f16)a.y,(f16)a.z,(f16)a.w,(f16)b.x,(f16)b.y,(f16)b.z,(f16)b.w};
      *(f16x8*)&sW[(size_t)i * 8] = v;
    }
    const int gc0 = half * 256 + wid * 32 + lm;
    const float b1v0 = b_ih1[gc0] + b_hh1[gc0];
    const float b1v1 = b_ih1[gc0 + 16] + b_hh1[gc0 + 16];
    __syncthreads();

    for (int t = set; t < Tt; t += 2) {
      if (t >= 16) {            // xw ring overwrite guard
        int s = 0;
        while (ldflag(FL + bg) < t - 15) { if (++s > SPINMAX) break; __builtin_amdgcn_s_sleep(1); }
      }
      CFENCE();
      f32x4 acc0 = {b1v0, b1v0, b1v0, b1v0};
      f32x4 acc1 = {b1v1, b1v1, b1v1, b1v1};
      const float* xr = x + ((size_t)(bg * 16 + lm) * Tt + t) * Ii + lk8;
      #pragma unroll
      for (int kc = 0; kc < 8; ++kc) {
        float4 a = *(const float4*)(xr + kc * 32);
        float4 b = *(const float4*)(xr + kc * 32 + 4);
        f16x8 A{(f16)a.x,(f16)a.y,(f16)a.z,(f16)a.w,(f16)b.x,(f16)b.y,(f16)b.z,(f16)b.w};
        acc0 = mfma16(A, *(const f16x8*)&sW[((size_t)(kc * 4 + lgrp) * 256 + wid * 32 + lm) * 8], acc0);
        acc1 = mfma16(A, *(const f16x8*)&sW[((size_t)(kc * 4 + lgrp) * 256 + wid * 32 + 16 + lm) * 8], acc1);
      }
      f16* dst = xwr + ((size_t)(t & 15) * 8 + bg) * 8192;
      f16x4 p0{(f16)acc0[0], (f16)acc0[1], (f16)acc0[2], (f16)acc0[3]};
      f16x4 p1{(f16)acc1[0], (f16)acc1[1], (f16)acc1[2], (f16)acc1[3]};
      st64cc(dst + (half * 16 + wid * 2 + 0) * 256 + lm * 16 + lgrp * 4, p0);
      st64cc(dst + (half * 16 + wid * 2 + 1) * 256 + lm * 16 + lgrp * 4, p1);
      VMFENCE();
      if (tid == 0) stflag(FL + 32 + (bg * 2 + set) * 2 + half, t + 1);
    }
    if (tid == 0) stflag(FL + 32 + (bg * 2 + set) * 2 + half, Tt + 2);
  }
}

extern "C" void kernel_launch(void* const* d_in, const int* in_sizes, int n_in,
                              void* d_out, int out_size, void* d_ws, size_t ws_size,
                              hipStream_t stream) {
  (void)in_sizes; (void)n_in; (void)out_size; (void)ws_size;
  const float* x     = (const float*)d_in[0];
  const float* w_ih1 = (const float*)d_in[1];
  const float* w_hh1 = (const float*)d_in[2];
  const float* b_ih1 = (const float*)d_in[3];
  const float* b_hh1 = (const float*)d_in[4];
  const float* w_ih2 = (const float*)d_in[5];
  const float* w_hh2 = (const float*)d_in[6];
  const float* b_ih2 = (const float*)d_in[7];
  const float* b_hh2 = (const float*)d_in[8];
  const float* w_out = (const float*)d_in[9];
  const float* b_out = (const float*)d_in[10];
  float* out = (float*)d_out;
  char* ws = (char*)d_ws;

  hipMemsetAsync(ws, 0, 4096, stream);   // flags
  hipLaunchKernelGGL(prep_weights, dim3(512), dim3(512), 0, stream, w_hh1, w_hh2, ws);
  hipLaunchKernelGGL(rnn_main, dim3(144), dim3(512), 0, stream,
                     x, w_ih1, w_ih2, b_ih1, b_hh1, b_ih2, b_hh2,
                     w_out, b_out, out, ws);
}